// Round 9
// baseline (266.073 us; speedup 1.0000x reference)
//
#include <hip/hip_runtime.h>

typedef __attribute__((ext_vector_type(8))) short short8;
typedef __attribute__((ext_vector_type(4))) float f32x4;
typedef __attribute__((ext_vector_type(16))) float f32x16;
typedef __attribute__((ext_vector_type(4))) unsigned int u32x4;

#define AS1(p) ((const __attribute__((address_space(1))) void*)(p))
#define AS3(p) ((__attribute__((address_space(3))) void*)(p))

#define B_ 4
#define T_ 2048
#define C_ 1024
#define H_ 16
#define D_ 64
#define M_ (B_*T_)   // 8192

__device__ __forceinline__ unsigned short f2bf(float f) {
  union { float f; unsigned u; } v; v.f = f;
  return (unsigned short)((v.u + 0x7fffu + ((v.u >> 16) & 1u)) >> 16);
}

__device__ __forceinline__ unsigned cvt_pk_bf16(float lo, float hi2) {
  unsigned r;
  asm("v_cvt_pk_bf16_f32 %0, %1, %2" : "=v"(r) : "v"(lo), "v"(hi2));
  return r;
}

// ---------------- cast fp32 -> bf16 ----------------
__global__ void cast_f32_bf16(const float* __restrict__ in, unsigned short* __restrict__ out, int n) {
  int i = (blockIdx.x * blockDim.x + threadIdx.x) * 4;
  int stride = gridDim.x * blockDim.x * 4;
  for (; i < n; i += stride) {
    float4 f = *reinterpret_cast<const float4*>(in + i);
    ushort4 o;
    o.x = f2bf(f.x); o.y = f2bf(f.y); o.z = f2bf(f.z); o.w = f2bf(f.w);
    *reinterpret_cast<ushort4*>(out + i) = o;
  }
}

// ---------------- GEMM: C[M][N] = A[M][K] * Bt[N][K]^T ----------------
template<int EPI>
__global__ __launch_bounds__(256) void gemm_bt(
    const unsigned short* __restrict__ A, const unsigned short* __restrict__ Bt,
    float* __restrict__ Cout, int M, int N, int K,
    unsigned short* __restrict__ qb, unsigned short* __restrict__ kb,
    unsigned short* __restrict__ vtb) {
  __shared__ unsigned short As[128 * 32];
  __shared__ unsigned short Bs[128 * 32];
  const int tid = threadIdx.x;
  const int lane = tid & 63;
  const int w = tid >> 6;
  const int wr = w >> 1, wc = w & 1;
  const int lr = lane & 15, lg = lane >> 4;
  const int ntiles = N >> 7;
  const int mt = blockIdx.x / ntiles, nt = blockIdx.x % ntiles;
  const int m0 = mt << 7, n0 = nt << 7;

  f32x4 acc[4][4];
  #pragma unroll
  for (int i = 0; i < 4; i++)
    #pragma unroll
    for (int j = 0; j < 4; j++) acc[i][j] = (f32x4){0.f, 0.f, 0.f, 0.f};

  const int wbase = tid & ~63;
  for (int k0 = 0; k0 < K; k0 += 32) {
    #pragma unroll
    for (int t = 0; t < 2; t++) {
      int slot = t * 256 + tid;
      int row = slot >> 2, kg = slot & 3;
      const unsigned short* ga = A + (size_t)(m0 + row) * K + k0 + kg * 8;
      char* la = (char*)As + (size_t)(t * 256 + wbase) * 16;
      __builtin_amdgcn_global_load_lds(AS1(ga), AS3(la), 16, 0, 0);
      const unsigned short* gb = Bt + (size_t)(n0 + row) * K + k0 + kg * 8;
      char* lb = (char*)Bs + (size_t)(t * 256 + wbase) * 16;
      __builtin_amdgcn_global_load_lds(AS1(gb), AS3(lb), 16, 0, 0);
    }
    __syncthreads();
    short8 af[4], bf[4];
    #pragma unroll
    for (int i = 0; i < 4; i++) {
      af[i] = *reinterpret_cast<const short8*>(&As[(wr * 64 + i * 16 + lr) * 32 + lg * 8]);
      bf[i] = *reinterpret_cast<const short8*>(&Bs[(wc * 64 + i * 16 + lr) * 32 + lg * 8]);
    }
    #pragma unroll
    for (int i = 0; i < 4; i++)
      #pragma unroll
      for (int j = 0; j < 4; j++)
        acc[i][j] = __builtin_amdgcn_mfma_f32_16x16x32_bf16(af[i], bf[j], acc[i][j], 0, 0, 0);
    __syncthreads();
  }

  #pragma unroll
  for (int i = 0; i < 4; i++) {
    #pragma unroll
    for (int j = 0; j < 4; j++) {
      #pragma unroll
      for (int r = 0; r < 4; r++) {
        int row = m0 + wr * 64 + i * 16 + lg * 4 + r;
        int col = n0 + wc * 64 + j * 16 + lr;
        float v = acc[i][j][r];
        if (EPI == 0) {
          Cout[(size_t)row * N + col] = v;
        } else {
          int which = col >> 10;
          int c = col & 1023;
          int h = c >> 6, d = c & 63;
          int b = row >> 11, t2 = row & 2047;
          if (which == 0) {
            qb[(((size_t)(b * H_ + h)) * T_ + t2) * D_ + d] = f2bf(v * 0.125f);
          } else if (which == 1) {
            kb[(((size_t)(b * H_ + h)) * T_ + t2) * D_ + d] = f2bf(v);
          } else {
            vtb[(((size_t)(b * H_ + h)) * D_ + d) * T_ + t2] = f2bf(v);
          }
        }
      }
    }
  }
}

// ---------------- flash attention (causal), 4 waves, 32x32 MFMA ----------------
// Swapped QK^T: S^T = mfma(K, Q)  -> col(lane&31)=q, row=k (in-register softmax).
// PV as O^T = mfma(V^T, P^T)      -> col(lane&31)=q, row=d (per-lane rescale).
// R9: tree-reduced max/sum, defer-max (THR=8), forced V-reg prefetch, setprio.
__global__ __launch_bounds__(256, 4) void attn_fwd(
    const unsigned short* __restrict__ qb, const unsigned short* __restrict__ kb,
    const unsigned short* __restrict__ vtb, unsigned short* __restrict__ ob) {
  __shared__ unsigned short Kl[2 * 64 * 64];  // double-buffered K tile, XOR-swizzled
  const int tid = threadIdx.x;
  const int lane = tid & 63;
  const int w = tid >> 6;          // 0..3
  const int q31 = lane & 31;
  const int hi = lane >> 5;

  const int bid = blockIdx.x;
  const int bh = (bid & 7) * 8 + ((bid >> 3) & 7);  // all 16 q-tiles of a head on one XCD
  const int qt = 15 - (bid >> 6);                   // heavy q-tiles dispatch first
  const int qb0 = qt << 7;
  const int b = bh >> 4, h = bh & 15;

  const unsigned short* Q  = qb  + (size_t)bh * T_ * D_;
  const unsigned short* Kp = kb  + (size_t)bh * T_ * D_;
  const unsigned short* Vt = vtb + (size_t)bh * D_ * T_;

  const int qlo = qb0 + w * 32;
  const int qg = qlo + q31;       // this lane's q row
  const int qmax = qlo + 31;

  // Q fragments (B-operand): lane holds Q[qg][ch*16 + hi*8 + 0..7]
  short8 qf[4];
  #pragma unroll
  for (int ch = 0; ch < 4; ch++)
    qf[ch] = *reinterpret_cast<const short8*>(Q + (size_t)qg * D_ + ch * 16 + hi * 8);

  f32x16 acc0, acc1;
  #pragma unroll
  for (int r = 0; r < 16; r++) { acc0[r] = 0.f; acc1[r] = 0.f; }
  float mrun = -INFINITY, lrun = 0.f;

  // stage K tile k0 into buf (linear LDS dest, inverse-swizzled global source)
  auto stage = [&](int buf, int k0) {
    #pragma unroll
    for (int sh = 0; sh < 2; sh++) {
      int s = sh * 256 + tid;
      int row = s >> 3;
      int xlin = (s & 7) * 16;
      int src = xlin ^ ((row & 7) << 4);
      const unsigned short* g = Kp + (size_t)(k0 + row) * D_ + (src >> 1);
      char* l = (char*)Kl + buf * 8192 + (size_t)(sh * 256 + (tid & ~63)) * 16;
      __builtin_amdgcn_global_load_lds(AS1(g), AS3(l), 16, 0, 0);
    }
  };

  const int nt = qb0 / 64 + 2;
  stage(0, 0);
  __syncthreads();

  for (int t = 0; t < nt; t++) {
    const int k0 = t * 64;
    if (t + 1 < nt) stage((t + 1) & 1, k0 + 64);

    if (k0 <= qmax) {  // wave-uniform: skip fully-masked tiles
      // ---- V prefetch into registers; sched_barrier pins the issue point ----
      short8 vf[2][4];   // [ds][kc*2+ks]
      #pragma unroll
      for (int ds = 0; ds < 2; ds++)
        #pragma unroll
        for (int kc = 0; kc < 2; kc++)
          #pragma unroll
          for (int ks = 0; ks < 2; ks++)
            vf[ds][kc * 2 + ks] = *reinterpret_cast<const short8*>(
                Vt + (size_t)(ds * 32 + q31) * T_ + k0 + kc * 32 + ks * 16 + hi * 8);
      __builtin_amdgcn_sched_barrier(0);

      const char* kbase = (const char*)Kl + (t & 1) * 8192;

      // ---- QK^T: S^T[k][q], two 32-row kc subtiles ----
      f32x16 s0, s1;
      #pragma unroll
      for (int r = 0; r < 16; r++) { s0[r] = 0.f; s1[r] = 0.f; }
      __builtin_amdgcn_s_setprio(1);
      #pragma unroll
      for (int kc = 0; kc < 2; kc++) {
        const int row = kc * 32 + q31;
        const int sw = (row & 7) << 4;
        #pragma unroll
        for (int ch = 0; ch < 4; ch++) {
          const int cb = ch * 32 + hi * 16;
          short8 kf = *reinterpret_cast<const short8*>(kbase + row * 128 + (cb ^ sw));
          if (kc == 0) s0 = __builtin_amdgcn_mfma_f32_32x32x16_bf16(kf, qf[ch], s0, 0, 0, 0);
          else         s1 = __builtin_amdgcn_mfma_f32_32x32x16_bf16(kf, qf[ch], s1, 0, 0, 0);
        }
      }
      __builtin_amdgcn_s_setprio(0);

      // ---- causal mask (only near-diagonal tiles) ----
      if (k0 + 63 > qlo) {
        #pragma unroll
        for (int r = 0; r < 16; r++) {
          const int kl = (r & 3) + 8 * (r >> 2) + 4 * hi;
          if (k0 + kl > qg)      s0[r] = -INFINITY;
          if (k0 + 32 + kl > qg) s1[r] = -INFINITY;
        }
      }

      // ---- per-lane max, tree-reduced (depth 5, not serial-32) ----
      float tm[8];
      #pragma unroll
      for (int r = 0; r < 8; r++)
        tm[r] = fmaxf(fmaxf(s0[r], s0[r + 8]), fmaxf(s1[r], s1[r + 8]));
      #pragma unroll
      for (int off = 4; off > 0; off >>= 1)
        #pragma unroll
        for (int r = 0; r < off; r++) tm[r] = fmaxf(tm[r], tm[r + off]);
      float pmax = fmaxf(tm[0], __shfl_xor(tm[0], 32));

      // ---- defer-max (THR=8): skip O-rescale when max barely grew ----
      const float mnew = fmaxf(mrun, pmax);
      if (!__all(pmax - mrun <= 8.0f)) {
        const float alpha = __expf(mrun - mnew);
        lrun *= alpha;
        #pragma unroll
        for (int r = 0; r < 16; r++) { acc0[r] *= alpha; acc1[r] *= alpha; }
        mrun = mnew;
      }

      // ---- P = exp(S - mrun), sum tree-reduced ----
      #pragma unroll
      for (int r = 0; r < 16; r++) { s0[r] = __expf(s0[r] - mrun); s1[r] = __expf(s1[r] - mrun); }
      float ts[8];
      #pragma unroll
      for (int r = 0; r < 8; r++)
        ts[r] = (s0[r] + s0[r + 8]) + (s1[r] + s1[r + 8]);
      #pragma unroll
      for (int off = 4; off > 0; off >>= 1)
        #pragma unroll
        for (int r = 0; r < off; r++) ts[r] += ts[r + off];
      lrun += ts[0] + __shfl_xor(ts[0], 32);

      // ---- PV: O^T += V^T * P^T, per kc subtile ----
      #pragma unroll
      for (int kc = 0; kc < 2; kc++) {
        unsigned w8[8], rw8[8];
        #pragma unroll
        for (int j = 0; j < 8; j++) {
          float a = (kc == 0) ? s0[2 * j] : s1[2 * j];
          float bb = (kc == 0) ? s0[2 * j + 1] : s1[2 * j + 1];
          w8[j] = cvt_pk_bf16(a, bb);
        }
        #pragma unroll
        for (int j = 0; j < 8; j++) rw8[j] = (unsigned)__shfl_xor((int)w8[j], 32);

        __builtin_amdgcn_s_setprio(1);
        #pragma unroll
        for (int ks = 0; ks < 2; ks++) {
          // P^T B-fragment (k ascending): index map vs 32x32 C/D layout
          unsigned a0 = hi ? rw8[4 * ks + 2] : w8[4 * ks + 0];
          unsigned a1 = hi ? rw8[4 * ks + 3] : w8[4 * ks + 1];
          unsigned a2 = hi ? w8[4 * ks + 2]  : rw8[4 * ks + 0];
          unsigned a3 = hi ? w8[4 * ks + 3]  : rw8[4 * ks + 1];
          u32x4 pw = {a0, a1, a2, a3};
          union { u32x4 u; short8 s; } cv; cv.u = pw;
          #pragma unroll
          for (int ds = 0; ds < 2; ds++) {
            if (ds == 0) acc0 = __builtin_amdgcn_mfma_f32_32x32x16_bf16(vf[0][kc * 2 + ks], cv.s, acc0, 0, 0, 0);
            else         acc1 = __builtin_amdgcn_mfma_f32_32x32x16_bf16(vf[1][kc * 2 + ks], cv.s, acc1, 0, 0, 0);
          }
        }
        __builtin_amdgcn_s_setprio(0);
      }
    }
    __syncthreads();
  }

  // ---- epilogue: O^T[d][q] -> ob[b, q, h*64 + d], bf16 ----
  const float inv = 1.f / lrun;
  unsigned short* orow = ob + ((size_t)(b * T_ + qg)) * C_ + h * D_;
  #pragma unroll
  for (int ds = 0; ds < 2; ds++) {
    #pragma unroll
    for (int g = 0; g < 4; g++) {
      ushort4 o4;
      if (ds == 0) {
        o4.x = f2bf(acc0[4 * g + 0] * inv); o4.y = f2bf(acc0[4 * g + 1] * inv);
        o4.z = f2bf(acc0[4 * g + 2] * inv); o4.w = f2bf(acc0[4 * g + 3] * inv);
      } else {
        o4.x = f2bf(acc1[4 * g + 0] * inv); o4.y = f2bf(acc1[4 * g + 1] * inv);
        o4.z = f2bf(acc1[4 * g + 2] * inv); o4.w = f2bf(acc1[4 * g + 3] * inv);
      }
      *reinterpret_cast<ushort4*>(orow + ds * 32 + 8 * g + 4 * hi) = o4;
    }
  }
}

extern "C" void kernel_launch(void* const* d_in, const int* in_sizes, int n_in,
                              void* d_out, int out_size, void* d_ws, size_t ws_size,
                              hipStream_t stream) {
  const float* x = (const float*)d_in[0];
  const float* W_qkv = (const float*)d_in[1];
  const float* W_proj = (const float*)d_in[2];
  float* out = (float*)d_out;

  char* ws = (char*)d_ws;
  unsigned short* xb     = (unsigned short*)(ws);
  unsigned short* wqkvb  = (unsigned short*)(ws + 16777216);
  unsigned short* wprojb = (unsigned short*)(ws + 23068672);
  unsigned short* qb     = (unsigned short*)(ws + 25165824);
  unsigned short* kb     = (unsigned short*)(ws + 41943040);
  unsigned short* vtb    = (unsigned short*)(ws + 58720256);
  unsigned short* ob     = xb;  // reuse x_bf16 buffer

  const int nx = M_ * C_;
  const int nwqkv = 3 * C_ * C_;
  const int nwproj = C_ * C_;

  cast_f32_bf16<<<2048, 256, 0, stream>>>(x, xb, nx);
  cast_f32_bf16<<<2048, 256, 0, stream>>>(W_qkv, wqkvb, nwqkv);
  cast_f32_bf16<<<1024, 256, 0, stream>>>(W_proj, wprojb, nwproj);

  gemm_bt<1><<<(M_ / 128) * (3 * C_ / 128), 256, 0, stream>>>(
      xb, wqkvb, nullptr, M_, 3 * C_, C_, qb, kb, vtb);

  attn_fwd<<<B_ * H_ * (T_ / 128), 256, 0, stream>>>(qb, kb, vtb, ob);

  gemm_bt<0><<<(M_ / 128) * (C_ / 128), 256, 0, stream>>>(
      ob, wprojb, out, M_, C_, C_, nullptr, nullptr, nullptr);
}

// Round 10
// 241.212 us; speedup vs baseline: 1.1031x; 1.1031x over previous
//
#include <hip/hip_runtime.h>

typedef __attribute__((ext_vector_type(8))) short short8;
typedef __attribute__((ext_vector_type(4))) float f32x4;
typedef __attribute__((ext_vector_type(16))) float f32x16;
typedef __attribute__((ext_vector_type(4))) unsigned int u32x4;

#define AS1(p) ((const __attribute__((address_space(1))) void*)(p))
#define AS3(p) ((__attribute__((address_space(3))) void*)(p))

#define B_ 4
#define T_ 2048
#define C_ 1024
#define H_ 16
#define D_ 64
#define M_ (B_*T_)   // 8192

__device__ __forceinline__ unsigned short f2bf(float f) {
  union { float f; unsigned u; } v; v.f = f;
  return (unsigned short)((v.u + 0x7fffu + ((v.u >> 16) & 1u)) >> 16);
}

__device__ __forceinline__ unsigned cvt_pk_bf16(float lo, float hi2) {
  unsigned r;
  asm("v_cvt_pk_bf16_f32 %0, %1, %2" : "=v"(r) : "v"(lo), "v"(hi2));
  return r;
}

// ---------------- cast fp32 -> bf16 ----------------
__global__ void cast_f32_bf16(const float* __restrict__ in, unsigned short* __restrict__ out, int n) {
  int i = (blockIdx.x * blockDim.x + threadIdx.x) * 4;
  int stride = gridDim.x * blockDim.x * 4;
  for (; i < n; i += stride) {
    float4 f = *reinterpret_cast<const float4*>(in + i);
    ushort4 o;
    o.x = f2bf(f.x); o.y = f2bf(f.y); o.z = f2bf(f.z); o.w = f2bf(f.w);
    *reinterpret_cast<ushort4*>(out + i) = o;
  }
}

// ---------------- GEMM: C[M][N] = A[M][K] * Bt[N][K]^T ----------------
template<int EPI>
__global__ __launch_bounds__(256) void gemm_bt(
    const unsigned short* __restrict__ A, const unsigned short* __restrict__ Bt,
    float* __restrict__ Cout, int M, int N, int K,
    unsigned short* __restrict__ qb, unsigned short* __restrict__ kb,
    unsigned short* __restrict__ vtb) {
  __shared__ unsigned short As[128 * 32];
  __shared__ unsigned short Bs[128 * 32];
  const int tid = threadIdx.x;
  const int lane = tid & 63;
  const int w = tid >> 6;
  const int wr = w >> 1, wc = w & 1;
  const int lr = lane & 15, lg = lane >> 4;
  const int ntiles = N >> 7;
  const int mt = blockIdx.x / ntiles, nt = blockIdx.x % ntiles;
  const int m0 = mt << 7, n0 = nt << 7;

  f32x4 acc[4][4];
  #pragma unroll
  for (int i = 0; i < 4; i++)
    #pragma unroll
    for (int j = 0; j < 4; j++) acc[i][j] = (f32x4){0.f, 0.f, 0.f, 0.f};

  const int wbase = tid & ~63;
  for (int k0 = 0; k0 < K; k0 += 32) {
    #pragma unroll
    for (int t = 0; t < 2; t++) {
      int slot = t * 256 + tid;
      int row = slot >> 2, kg = slot & 3;
      const unsigned short* ga = A + (size_t)(m0 + row) * K + k0 + kg * 8;
      char* la = (char*)As + (size_t)(t * 256 + wbase) * 16;
      __builtin_amdgcn_global_load_lds(AS1(ga), AS3(la), 16, 0, 0);
      const unsigned short* gb = Bt + (size_t)(n0 + row) * K + k0 + kg * 8;
      char* lb = (char*)Bs + (size_t)(t * 256 + wbase) * 16;
      __builtin_amdgcn_global_load_lds(AS1(gb), AS3(lb), 16, 0, 0);
    }
    __syncthreads();
    short8 af[4], bf[4];
    #pragma unroll
    for (int i = 0; i < 4; i++) {
      af[i] = *reinterpret_cast<const short8*>(&As[(wr * 64 + i * 16 + lr) * 32 + lg * 8]);
      bf[i] = *reinterpret_cast<const short8*>(&Bs[(wc * 64 + i * 16 + lr) * 32 + lg * 8]);
    }
    #pragma unroll
    for (int i = 0; i < 4; i++)
      #pragma unroll
      for (int j = 0; j < 4; j++)
        acc[i][j] = __builtin_amdgcn_mfma_f32_16x16x32_bf16(af[i], bf[j], acc[i][j], 0, 0, 0);
    __syncthreads();
  }

  #pragma unroll
  for (int i = 0; i < 4; i++) {
    #pragma unroll
    for (int j = 0; j < 4; j++) {
      #pragma unroll
      for (int r = 0; r < 4; r++) {
        int row = m0 + wr * 64 + i * 16 + lg * 4 + r;
        int col = n0 + wc * 64 + j * 16 + lr;
        float v = acc[i][j][r];
        if (EPI == 0) {
          Cout[(size_t)row * N + col] = v;
        } else {
          int which = col >> 10;
          int c = col & 1023;
          int h = c >> 6, d = c & 63;
          int b = row >> 11, t2 = row & 2047;
          if (which == 0) {
            qb[(((size_t)(b * H_ + h)) * T_ + t2) * D_ + d] = f2bf(v * 0.125f);
          } else if (which == 1) {
            kb[(((size_t)(b * H_ + h)) * T_ + t2) * D_ + d] = f2bf(v);
          } else {
            vtb[(((size_t)(b * H_ + h)) * D_ + d) * T_ + t2] = f2bf(v);
          }
        }
      }
    }
  }
}

// ---------------- flash attention (causal), 4 waves, 32x32 MFMA ----------------
// Swapped QK^T: S^T = mfma(K, Q)  -> col(lane&31)=q, row=k (in-register softmax).
// PV as O^T = mfma(V^T, P^T)      -> col(lane&31)=q, row=d (per-lane rescale).
// R10 = R5 base (launch_bounds(256,2): AGPRs count against the unified file!)
//       + tree-reduced max/sum + defer-max (THR=8) + setprio around MFMA.
__global__ __launch_bounds__(256, 2) void attn_fwd(
    const unsigned short* __restrict__ qb, const unsigned short* __restrict__ kb,
    const unsigned short* __restrict__ vtb, unsigned short* __restrict__ ob) {
  __shared__ unsigned short Kl[2 * 64 * 64];  // double-buffered K tile, XOR-swizzled
  const int tid = threadIdx.x;
  const int lane = tid & 63;
  const int w = tid >> 6;          // 0..3
  const int q31 = lane & 31;
  const int hi = lane >> 5;

  const int bid = blockIdx.x;
  const int bh = (bid & 7) * 8 + ((bid >> 3) & 7);  // all 16 q-tiles of a head on one XCD
  const int qt = 15 - (bid >> 6);                   // heavy q-tiles dispatch first
  const int qb0 = qt << 7;
  const int b = bh >> 4, h = bh & 15;

  const unsigned short* Q  = qb  + (size_t)bh * T_ * D_;
  const unsigned short* Kp = kb  + (size_t)bh * T_ * D_;
  const unsigned short* Vt = vtb + (size_t)bh * D_ * T_;

  const int qlo = qb0 + w * 32;
  const int qg = qlo + q31;       // this lane's q row
  const int qmax = qlo + 31;

  // Q fragments (B-operand): lane holds Q[qg][ch*16 + hi*8 + 0..7]
  short8 qf[4];
  #pragma unroll
  for (int ch = 0; ch < 4; ch++)
    qf[ch] = *reinterpret_cast<const short8*>(Q + (size_t)qg * D_ + ch * 16 + hi * 8);

  f32x16 acc0, acc1;
  #pragma unroll
  for (int r = 0; r < 16; r++) { acc0[r] = 0.f; acc1[r] = 0.f; }
  float mrun = -INFINITY, lrun = 0.f;

  // stage K tile k0 into buf (linear LDS dest, inverse-swizzled global source)
  auto stage = [&](int buf, int k0) {
    #pragma unroll
    for (int sh = 0; sh < 2; sh++) {
      int s = sh * 256 + tid;
      int row = s >> 3;
      int xlin = (s & 7) * 16;
      int src = xlin ^ ((row & 7) << 4);
      const unsigned short* g = Kp + (size_t)(k0 + row) * D_ + (src >> 1);
      char* l = (char*)Kl + buf * 8192 + (size_t)(sh * 256 + (tid & ~63)) * 16;
      __builtin_amdgcn_global_load_lds(AS1(g), AS3(l), 16, 0, 0);
    }
  };

  const int nt = qb0 / 64 + 2;
  stage(0, 0);
  __syncthreads();

  for (int t = 0; t < nt; t++) {
    const int k0 = t * 64;
    if (t + 1 < nt) stage((t + 1) & 1, k0 + 64);

    if (k0 <= qmax) {  // wave-uniform: skip fully-masked tiles
      const char* kbase = (const char*)Kl + (t & 1) * 8192;

      // ---- QK^T: S^T[k][q], two 32-row kc subtiles ----
      f32x16 s0, s1;
      #pragma unroll
      for (int r = 0; r < 16; r++) { s0[r] = 0.f; s1[r] = 0.f; }
      __builtin_amdgcn_s_setprio(1);
      #pragma unroll
      for (int kc = 0; kc < 2; kc++) {
        const int row = kc * 32 + q31;
        const int sw = (row & 7) << 4;
        #pragma unroll
        for (int ch = 0; ch < 4; ch++) {
          const int cb = ch * 32 + hi * 16;
          short8 kf = *reinterpret_cast<const short8*>(kbase + row * 128 + (cb ^ sw));
          if (kc == 0) s0 = __builtin_amdgcn_mfma_f32_32x32x16_bf16(kf, qf[ch], s0, 0, 0, 0);
          else         s1 = __builtin_amdgcn_mfma_f32_32x32x16_bf16(kf, qf[ch], s1, 0, 0, 0);
        }
      }
      __builtin_amdgcn_s_setprio(0);

      // ---- causal mask (only near-diagonal tiles) ----
      if (k0 + 63 > qlo) {
        #pragma unroll
        for (int r = 0; r < 16; r++) {
          const int kl = (r & 3) + 8 * (r >> 2) + 4 * hi;
          if (k0 + kl > qg)      s0[r] = -INFINITY;
          if (k0 + 32 + kl > qg) s1[r] = -INFINITY;
        }
      }

      // ---- per-lane max, tree-reduced (depth ~5, not serial-32) ----
      float tm[8];
      #pragma unroll
      for (int r = 0; r < 8; r++)
        tm[r] = fmaxf(fmaxf(s0[r], s0[r + 8]), fmaxf(s1[r], s1[r + 8]));
      #pragma unroll
      for (int off = 4; off > 0; off >>= 1)
        #pragma unroll
        for (int r = 0; r < off; r++) tm[r] = fmaxf(tm[r], tm[r + off]);
      float pmax = fmaxf(tm[0], __shfl_xor(tm[0], 32));

      // ---- defer-max (THR=8): skip O-rescale when max barely grew ----
      if (!__all(pmax - mrun <= 8.0f)) {
        const float mnew = fmaxf(mrun, pmax);
        const float alpha = __expf(mrun - mnew);
        lrun *= alpha;
        #pragma unroll
        for (int r = 0; r < 16; r++) { acc0[r] *= alpha; acc1[r] *= alpha; }
        mrun = mnew;
      }

      // ---- P = exp(S - mrun), sum tree-reduced ----
      #pragma unroll
      for (int r = 0; r < 16; r++) { s0[r] = __expf(s0[r] - mrun); s1[r] = __expf(s1[r] - mrun); }
      float ts[8];
      #pragma unroll
      for (int r = 0; r < 8; r++)
        ts[r] = (s0[r] + s0[r + 8]) + (s1[r] + s1[r + 8]);
      #pragma unroll
      for (int off = 4; off > 0; off >>= 1)
        #pragma unroll
        for (int r = 0; r < off; r++) ts[r] += ts[r + off];
      lrun += ts[0] + __shfl_xor(ts[0], 32);

      // ---- PV: O^T += V^T * P^T, per kc subtile (V loaded inline, R5-style) ----
      #pragma unroll
      for (int kc = 0; kc < 2; kc++) {
        unsigned w8[8], rw8[8];
        #pragma unroll
        for (int j = 0; j < 8; j++) {
          float a = (kc == 0) ? s0[2 * j] : s1[2 * j];
          float bb = (kc == 0) ? s0[2 * j + 1] : s1[2 * j + 1];
          w8[j] = cvt_pk_bf16(a, bb);
        }
        #pragma unroll
        for (int j = 0; j < 8; j++) rw8[j] = (unsigned)__shfl_xor((int)w8[j], 32);

        __builtin_amdgcn_s_setprio(1);
        #pragma unroll
        for (int ks = 0; ks < 2; ks++) {
          // P^T B-fragment (k ascending): index map vs 32x32 C/D layout
          unsigned a0 = hi ? rw8[4 * ks + 2] : w8[4 * ks + 0];
          unsigned a1 = hi ? rw8[4 * ks + 3] : w8[4 * ks + 1];
          unsigned a2 = hi ? w8[4 * ks + 2]  : rw8[4 * ks + 0];
          unsigned a3 = hi ? w8[4 * ks + 3]  : rw8[4 * ks + 1];
          u32x4 pw = {a0, a1, a2, a3};
          union { u32x4 u; short8 s; } cv; cv.u = pw;
          const int kb2 = k0 + kc * 32 + ks * 16;
          #pragma unroll
          for (int ds = 0; ds < 2; ds++) {
            short8 vf = *reinterpret_cast<const short8*>(
                Vt + (size_t)(ds * 32 + q31) * T_ + kb2 + hi * 8);
            if (ds == 0) acc0 = __builtin_amdgcn_mfma_f32_32x32x16_bf16(vf, cv.s, acc0, 0, 0, 0);
            else         acc1 = __builtin_amdgcn_mfma_f32_32x32x16_bf16(vf, cv.s, acc1, 0, 0, 0);
          }
        }
        __builtin_amdgcn_s_setprio(0);
      }
    }
    __syncthreads();
  }

  // ---- epilogue: O^T[d][q] -> ob[b, q, h*64 + d], bf16 ----
  const float inv = 1.f / lrun;
  unsigned short* orow = ob + ((size_t)(b * T_ + qg)) * C_ + h * D_;
  #pragma unroll
  for (int ds = 0; ds < 2; ds++) {
    #pragma unroll
    for (int g = 0; g < 4; g++) {
      ushort4 o4;
      if (ds == 0) {
        o4.x = f2bf(acc0[4 * g + 0] * inv); o4.y = f2bf(acc0[4 * g + 1] * inv);
        o4.z = f2bf(acc0[4 * g + 2] * inv); o4.w = f2bf(acc0[4 * g + 3] * inv);
      } else {
        o4.x = f2bf(acc1[4 * g + 0] * inv); o4.y = f2bf(acc1[4 * g + 1] * inv);
        o4.z = f2bf(acc1[4 * g + 2] * inv); o4.w = f2bf(acc1[4 * g + 3] * inv);
      }
      *reinterpret_cast<ushort4*>(orow + ds * 32 + 8 * g + 4 * hi) = o4;
    }
  }
}

extern "C" void kernel_launch(void* const* d_in, const int* in_sizes, int n_in,
                              void* d_out, int out_size, void* d_ws, size_t ws_size,
                              hipStream_t stream) {
  const float* x = (const float*)d_in[0];
  const float* W_qkv = (const float*)d_in[1];
  const float* W_proj = (const float*)d_in[2];
  float* out = (float*)d_out;

  char* ws = (char*)d_ws;
  unsigned short* xb     = (unsigned short*)(ws);
  unsigned short* wqkvb  = (unsigned short*)(ws + 16777216);
  unsigned short* wprojb = (unsigned short*)(ws + 23068672);
  unsigned short* qb     = (unsigned short*)(ws + 25165824);
  unsigned short* kb     = (unsigned short*)(ws + 41943040);
  unsigned short* vtb    = (unsigned short*)(ws + 58720256);
  unsigned short* ob     = xb;  // reuse x_bf16 buffer

  const int nx = M_ * C_;
  const int nwqkv = 3 * C_ * C_;
  const int nwproj = C_ * C_;

  cast_f32_bf16<<<2048, 256, 0, stream>>>(x, xb, nx);
  cast_f32_bf16<<<2048, 256, 0, stream>>>(W_qkv, wqkvb, nwqkv);
  cast_f32_bf16<<<1024, 256, 0, stream>>>(W_proj, wprojb, nwproj);

  gemm_bt<1><<<(M_ / 128) * (3 * C_ / 128), 256, 0, stream>>>(
      xb, wqkvb, nullptr, M_, 3 * C_, C_, qb, kb, vtb);

  attn_fwd<<<B_ * H_ * (T_ / 128), 256, 0, stream>>>(qb, kb, vtb, ob);

  gemm_bt<0><<<(M_ / 128) * (C_ / 128), 256, 0, stream>>>(
      ob, wprojb, out, M_, C_, C_, nullptr, nullptr, nullptr);
}